// Round 11
// baseline (99.857 us; speedup 1.0000x reference)
//
#include <hip/hip_runtime.h>
#include <stdint.h>

typedef unsigned long long u64;
typedef unsigned int u32;
typedef float f2 __attribute__((ext_vector_type(2)));

// ---- cross-lane helpers ----
__device__ __forceinline__ float dpp_shr1_f(float v, int fill_bits) {
  // within each 16-lane row: lane i <- lane i-1; row-lead takes fill
  return __int_as_float(__builtin_amdgcn_update_dpp(
      fill_bits, __float_as_int(v), 0x111 /*row_shr:1*/, 0xF, 0xF, false));
}
__device__ __forceinline__ int dpp_shr1_i(int v) {
  return __builtin_amdgcn_update_dpp(0, v, 0x111, 0xF, 0xF, false);
}
__device__ __forceinline__ float rdlane_f(float v, int lane) {
  return __int_as_float(__builtin_amdgcn_readlane(__float_as_int(v), lane));
}
// order-preserving float-bits -> u32 (monotone over all floats incl. negatives)
__device__ __forceinline__ u32 fkey(u32 s) {
  return s ^ ((u32)((int)s >> 31) | 0x80000000u);
}

// pair records for 128-pt chunks: pair (n0 = k*128+t, n1 = n0+64), t=0..63
// rec0 = {-2x0,-2x1,-2y0,-2y1}, rec1 = {-2z0,-2z1, pn0, pn1}
// x(-2) is exact so q*(-2p) == -2*inner bit-exactly; pn in numpy order.
__global__ void prep_pack2(const float* __restrict__ pc, float4* __restrict__ pp,
                           int B, int N) {
  int r = blockIdx.x * blockDim.x + threadIdx.x;  // pair id
  int H = N >> 1;
  if (r >= B * H) return;
  int b = r / H;
  int j = r - b * H;
  int k = j >> 6, t = j & 63;
  int n0 = (k << 7) + t, n1 = n0 + 64;
  const float* p = pc + (size_t)b * 3 * N;
  float x0 = p[n0], x1 = p[n1];
  float y0 = p[N + n0], y1 = p[N + n1];
  float z0 = p[2 * N + n0], z1 = p[2 * N + n1];
  float pn0 = __fadd_rn(__fadd_rn(__fmul_rn(x0, x0), __fmul_rn(y0, y0)),
                        __fmul_rn(z0, z0));
  float pn1 = __fadd_rn(__fadd_rn(__fmul_rn(x1, x1), __fmul_rn(y1, y1)),
                        __fmul_rn(z1, z1));
  pp[2 * r] = make_float4(__fmul_rn(x0, -2.0f), __fmul_rn(x1, -2.0f),
                          __fmul_rn(y0, -2.0f), __fmul_rn(y1, -2.0f));
  pp[2 * r + 1] = make_float4(__fmul_rn(z0, -2.0f), __fmul_rn(z1, -2.0f),
                              pn0, pn1);
}

struct Q4 { float4 a, b, c, d; };

template <bool PACKED>
__global__ __launch_bounds__(256, 8) void knn11(
    const float* __restrict__ pc,    // (B,3,N)
    const float* __restrict__ qc,    // (B,3,M)
    const float* __restrict__ temp,  // scalar
    const float4* __restrict__ pp,   // packed pair records
    float* __restrict__ out,         // (B,3,M)
    int B, int N, int M) {
#pragma clang fp contract(off)
  const float INF = __int_as_float(0x7f800000);
  const int NINF_BITS = (int)0xff800000;

  int tid = threadIdx.x;
  int lane = tid & 63;
  // wave-uniform pair id -> scalar bases (saddr addressing)
  int pairid = __builtin_amdgcn_readfirstlane(blockIdx.x * 4 + (tid >> 6));
  int b = pairid >> 10;              // M=2048 -> 1024 pairs per batch
  int qa = (pairid << 1) & 2047;     // even query
  int qb = qa + 1;                   // odd query (same batch b)

  float qxA = qc[(b * 3 + 0) * M + qa];
  float qyA = qc[(b * 3 + 1) * M + qa];
  float qzA = qc[(b * 3 + 2) * M + qa];
  float qnA = __fadd_rn(__fadd_rn(__fmul_rn(qxA, qxA), __fmul_rn(qyA, qyA)),
                        __fmul_rn(qzA, qzA));
  float qxB = qc[(b * 3 + 0) * M + qb];
  float qyB = qc[(b * 3 + 1) * M + qb];
  float qzB = qc[(b * 3 + 2) * M + qb];
  float qnB = __fadd_rn(__fadd_rn(__fmul_rn(qxB, qxB), __fmul_rn(qyB, qyB)),
                        __fmul_rn(qzB, qzB));

  // two distributed top-16 lists: lane (l&15) holds entry (l&15), ascending;
  // all four 16-lane rows mirror the same list (updates are wave-uniform).
  float valA = INF, valB = INF;
  int idxA = 0, idxB = 0;
  float threshA = INF, threshB = INF;

  const float* __restrict__ pcb = pc + (size_t)b * 3 * N;

  // merged round: one candidate from EACH query per iteration; the two
  // val/idx chains are independent -> compiler interleaves them (stall fill)
  auto half2 = [&](float dA, float dB, int g) {
    u64 mA = __ballot(dA < threshA);
    u64 mB = __ballot(dB < threshB);
    if (mA | mB) {
      do {
        int sA = __ffsll((long long)mA) - 1;  // -1 if empty
        int sB = __ffsll((long long)mB) - 1;
        float cvA = rdlane_f(dA, sA < 0 ? 0 : sA);  // SGPR scalar
        float cvB = rdlane_f(dB, sB < 0 ? 0 : sB);
        if (sA < 0) cvA = INF;               // scalar cselect, off-chain
        if (sB < 0) cvB = INF;
        int ciA = g + sA;                    // unused when cvA==INF
        int ciB = g + sB;
        // A chain
        float pvA = dpp_shr1_f(valA, NINF_BITS);
        int piA = dpp_shr1_i(idxA);
        bool pA = cvA < valA;                // strict < keeps tie-break
        bool p2A = cvA < pvA;
        valA = __builtin_amdgcn_fmed3f(valA, pvA, cvA);
        idxA = pA ? (p2A ? piA : ciA) : idxA;
        // B chain (independent)
        float pvB = dpp_shr1_f(valB, NINF_BITS);
        int piB = dpp_shr1_i(idxB);
        bool pB = cvB < valB;
        bool p2B = cvB < pvB;
        valB = __builtin_amdgcn_fmed3f(valB, pvB, cvB);
        idxB = pB ? (p2B ? piB : ciB) : idxB;
        mA &= mA - 1;                        // 0-safe
        mB &= mB - 1;
      } while (mA | mB);
      threshA = rdlane_f(valA, 15);
      threshB = rdlane_f(valB, 15);
    }
  };

  auto distQ = [&](float4 c0, float4 c1, float qx_, float qy_, float qz_,
                   float qn_) -> f2 {
    // d2 = (qn+pn) + (qx*(-2px)+qy*(-2py)+qz*(-2pz)) == reference bit-exact
    f2 px = {c0.x, c0.y}, py = {c0.z, c0.w};
    f2 pz = {c1.x, c1.y}, pw = {c1.z, c1.w};
    f2 qx2 = {qx_, qx_}, qy2 = {qy_, qy_}, qz2 = {qz_, qz_}, qn2 = {qn_, qn_};
    f2 s1 = qx2 * px;
    f2 s2 = qy2 * py;
    f2 s3 = qz2 * pz;
    f2 t = (s1 + s2) + s3;
    return (qn2 + pw) + t;
  };

  // 64-lane bitonic warmup: exact top-16-of-64 seed (key = dist|idx)
  auto bitonic16 = [&](float d0, float& val, int& idx, float& thresh) {
    u64 key = ((u64)fkey(__float_as_uint(d0)) << 32) | (u32)lane;
#pragma unroll
    for (int k = 2; k <= 64; k <<= 1) {
#pragma unroll
      for (int j = k >> 1; j >= 1; j >>= 1) {
        u32 klo = (u32)key, khi = (u32)(key >> 32);
        u32 plo = (u32)__shfl_xor((int)klo, j);
        u32 phi = (u32)__shfl_xor((int)khi, j);
        u64 pkey = ((u64)phi << 32) | plo;
        bool keepMin = ((lane & j) == 0) == ((lane & k) == 0);
        bool lt = key < pkey;
        key = (lt == keepMin) ? key : pkey;
      }
    }
    int src = (lane & 15) << 2;  // distribute entries 0..15 to all rows
    u32 lo = (u32)__builtin_amdgcn_ds_bpermute(src, (int)(u32)key);
    u32 hi = (u32)__builtin_amdgcn_ds_bpermute(src, (int)(key >> 32));
    idx = (int)lo;
    val = __uint_as_float(hi ^ (((int)hi >= 0) ? 0xFFFFFFFFu : 0x80000000u));
    thresh = rdlane_f(val, 15);
  };

  if (PACKED) {
    const char* sbase = (const char*)(pp + (size_t)b * N);
    u32 vo = (u32)(lane << 5);
    auto LD = [&](int dc) {
      const char* p = sbase + ((size_t)dc << 12) + vo;
      Q4 r;
      r.a = *(const float4*)(p);
      r.b = *(const float4*)(p + 16);
      r.c = *(const float4*)(p + 2048);
      r.d = *(const float4*)(p + 2064);
      return r;
    };

    f2 dA1, dB1, dA2, dB2;
    Q4 A = LD(0);
    dA1 = distQ(A.a, A.b, qxA, qyA, qzA, qnA);
    dB1 = distQ(A.a, A.b, qxB, qyB, qzB, qnB);
    dA2 = distQ(A.c, A.d, qxA, qyA, qzA, qnA);
    dB2 = distQ(A.c, A.d, qxB, qyB, qzB, qnB);
    A = LD(1);  // issue next loads; covered by warmup + inserts below
    // dual warmups (independent chains interleave)
    bitonic16(dA1.x, valA, idxA, threshA);
    bitonic16(dB1.x, valB, idxB, threshB);
    half2(dA1.y, dB1.y, 64);
    half2(dA2.x, dB2.x, 128);
    half2(dA2.y, dB2.y, 192);
#pragma unroll 1
    for (int k = 1; k < 31; ++k) {
      dA1 = distQ(A.a, A.b, qxA, qyA, qzA, qnA);
      dB1 = distQ(A.a, A.b, qxB, qyB, qzB, qnB);
      dA2 = distQ(A.c, A.d, qxA, qyA, qzA, qnA);
      dB2 = distQ(A.c, A.d, qxB, qyB, qzB, qnB);
      A = LD(k + 1);  // issue next; hidden under insert halves
      int g = k << 8;
      half2(dA1.x, dB1.x, g);
      half2(dA1.y, dB1.y, g + 64);
      half2(dA2.x, dB2.x, g + 128);
      half2(dA2.y, dB2.y, g + 192);
    }
    dA1 = distQ(A.a, A.b, qxA, qyA, qzA, qnA);
    dB1 = distQ(A.a, A.b, qxB, qyB, qzB, qnB);
    dA2 = distQ(A.c, A.d, qxA, qyA, qzA, qnA);
    dB2 = distQ(A.c, A.d, qxB, qyB, qzB, qnB);
    half2(dA1.x, dB1.x, 31 << 8);
    half2(dA1.y, dB1.y, (31 << 8) + 64);
    half2(dA2.x, dB2.x, (31 << 8) + 128);
    half2(dA2.y, dB2.y, (31 << 8) + 192);
  } else {
    // fallback: no warmup (merged flood is correct, just slower)
#pragma unroll 1
    for (int g = 0; g < N; g += 64) {
      int n = g + lane;
      float x = pcb[n], y = pcb[N + n], z = pcb[2 * N + n];
      float pn = __fadd_rn(__fadd_rn(__fmul_rn(x, x), __fmul_rn(y, y)),
                           __fmul_rn(z, z));
      float nx = __fmul_rn(x, -2.0f), ny = __fmul_rn(y, -2.0f),
            nz = __fmul_rn(z, -2.0f);
      float tA = __fadd_rn(__fadd_rn(__fmul_rn(qxA, nx), __fmul_rn(qyA, ny)),
                           __fmul_rn(qzA, nz));
      float d2A = __fadd_rn(__fadd_rn(qnA, pn), tA);
      float tB = __fadd_rn(__fadd_rn(__fmul_rn(qxB, nx), __fmul_rn(qyB, ny)),
                           __fmul_rn(qzB, nz));
      float d2B = __fadd_rn(__fadd_rn(qnB, pn), tB);
      half2(d2A, d2B, g);
    }
  }

  // ---- finisher (np-faithful), once per query ----
  float Tv = temp[0];
  float sigma = fmaxf(__fmul_rn(Tv, Tv), 1e-4f);
  float sp = __fadd_rn(sigma, 1e-8f);
  auto finish = [&](int idx_, float qx_, float qy_, float qz_, int qout) {
    int n = idx_;
    float px = pcb[n], py = pcb[N + n], pz = pcb[2 * N + n];
    float dx = __fsub_rn(px, qx_), dy = __fsub_rn(py, qy_),
          dz = __fsub_rn(pz, qz_);
    float d2w = __fadd_rn(__fadd_rn(__fmul_rn(dx, dx), __fmul_rn(dy, dy)),
                          __fmul_rn(dz, dz));
    float a = -__fdiv_rn(d2w, sp);  // -dist; softmax shift-invariant
    float m = rdlane_f(a, 0);       // entry 0 = nearest (sorted ascending)
    float e = expf(__fsub_rn(a, m));
    float Z = e;
#pragma unroll
    for (int d = 1; d < 16; d <<= 1) Z += __shfl_xor(Z, d, 16);
    float w = __fdiv_rn(e, Z);      // normalized weight
    float sx = __fmul_rn(px, w), sy = __fmul_rn(py, w), sz = __fmul_rn(pz, w);
#pragma unroll
    for (int d = 1; d < 16; d <<= 1) {
      sx += __shfl_xor(sx, d, 16);
      sy += __shfl_xor(sy, d, 16);
      sz += __shfl_xor(sz, d, 16);
    }
    if (lane < 3) {
      float r = (lane == 0) ? sx : ((lane == 1) ? sy : sz);
      out[(b * 3 + lane) * M + qout] = r;
    }
  };
  finish(idxA, qxA, qyA, qzA, qa);
  finish(idxB, qxB, qyB, qzB, qb);
}

extern "C" void kernel_launch(void* const* d_in, const int* in_sizes, int n_in,
                              void* d_out, int out_size, void* d_ws, size_t ws_size,
                              hipStream_t stream) {
  const int B = 8, N = 8192, M = 2048;
  const float* pc = (const float*)d_in[0];
  const float* qc = (const float*)d_in[1];
  const float* temp = (const float*)d_in[2];
  float* out = (float*)d_out;

  size_t packBytes = (size_t)B * N * 16;  // B*N/2 pairs * 32B
  bool packed = (ws_size >= packBytes) && (d_ws != nullptr);

  int nblocks = (B * M) / 8;  // 2 queries per wave, 4 waves per block
  if (packed) {
    int R = B * (N >> 1);
    prep_pack2<<<dim3((R + 255) / 256), dim3(256), 0, stream>>>(
        pc, (float4*)d_ws, B, N);
    knn11<true><<<dim3(nblocks), dim3(256), 0, stream>>>(
        pc, qc, temp, (const float4*)d_ws, out, B, N, M);
  } else {
    knn11<false><<<dim3(nblocks), dim3(256), 0, stream>>>(
        pc, qc, temp, nullptr, out, B, N, M);
  }
}

// Round 12
// 95.554 us; speedup vs baseline: 1.0450x; 1.0450x over previous
//
#include <hip/hip_runtime.h>
#include <stdint.h>

typedef unsigned long long u64;
typedef unsigned int u32;
typedef float f2 __attribute__((ext_vector_type(2)));

// ---- cross-lane helpers ----
__device__ __forceinline__ float dpp_shr1_f(float v, int fill_bits) {
  // within each 16-lane row: lane i <- lane i-1; row-lead takes fill
  return __int_as_float(__builtin_amdgcn_update_dpp(
      fill_bits, __float_as_int(v), 0x111 /*row_shr:1*/, 0xF, 0xF, false));
}
__device__ __forceinline__ int dpp_shr1_i(int v) {
  return __builtin_amdgcn_update_dpp(0, v, 0x111, 0xF, 0xF, false);
}
__device__ __forceinline__ float dpp_shr2_f(float v, int fill_bits) {
  // lane i <- lane i-2 within row of 16; lanes 0,1 take fill
  return __int_as_float(__builtin_amdgcn_update_dpp(
      fill_bits, __float_as_int(v), 0x112 /*row_shr:2*/, 0xF, 0xF, false));
}
__device__ __forceinline__ int dpp_shr2_i(int v) {
  return __builtin_amdgcn_update_dpp(0, v, 0x112, 0xF, 0xF, false);
}
__device__ __forceinline__ float rdlane_f(float v, int lane) {
  return __int_as_float(__builtin_amdgcn_readlane(__float_as_int(v), lane));
}
// order-preserving float-bits -> u32 (monotone over all floats incl. negatives)
__device__ __forceinline__ u32 fkey(u32 s) {
  return s ^ ((u32)((int)s >> 31) | 0x80000000u);
}

// pair records for 128-pt chunks: pair (n0 = k*128+t, n1 = n0+64), t=0..63
// rec0 = {-2x0,-2x1,-2y0,-2y1}, rec1 = {-2z0,-2z1, pn0, pn1}
// x(-2) is exact so q*(-2p) == -2*inner bit-exactly; pn in numpy order.
__global__ void prep_pack2(const float* __restrict__ pc, float4* __restrict__ pp,
                           int B, int N) {
  int r = blockIdx.x * blockDim.x + threadIdx.x;  // pair id
  int H = N >> 1;
  if (r >= B * H) return;
  int b = r / H;
  int j = r - b * H;
  int k = j >> 6, t = j & 63;
  int n0 = (k << 7) + t, n1 = n0 + 64;
  const float* p = pc + (size_t)b * 3 * N;
  float x0 = p[n0], x1 = p[n1];
  float y0 = p[N + n0], y1 = p[N + n1];
  float z0 = p[2 * N + n0], z1 = p[2 * N + n1];
  float pn0 = __fadd_rn(__fadd_rn(__fmul_rn(x0, x0), __fmul_rn(y0, y0)),
                        __fmul_rn(z0, z0));
  float pn1 = __fadd_rn(__fadd_rn(__fmul_rn(x1, x1), __fmul_rn(y1, y1)),
                        __fmul_rn(z1, z1));
  pp[2 * r] = make_float4(__fmul_rn(x0, -2.0f), __fmul_rn(x1, -2.0f),
                          __fmul_rn(y0, -2.0f), __fmul_rn(y1, -2.0f));
  pp[2 * r + 1] = make_float4(__fmul_rn(z0, -2.0f), __fmul_rn(z1, -2.0f),
                              pn0, pn1);
}

struct Q4 { float4 a, b, c, d; };

template <bool PACKED>
__global__ __launch_bounds__(256, 8) void knn12(
    const float* __restrict__ pc,    // (B,3,N)
    const float* __restrict__ qc,    // (B,3,M)
    const float* __restrict__ temp,  // scalar
    const float4* __restrict__ pp,   // packed pair records
    float* __restrict__ out,         // (B,3,M)
    int B, int N, int M) {
#pragma clang fp contract(off)
  const float INF = __int_as_float(0x7f800000);
  const int NINF_BITS = (int)0xff800000;
  const float NINF = __int_as_float(NINF_BITS);

  int tid = threadIdx.x;
  int lane = tid & 63;
  // wave-uniform query id -> scalar bases (saddr addressing, no VALU addr math)
  int qid = __builtin_amdgcn_readfirstlane(blockIdx.x * 4 + (tid >> 6));
  int b = qid >> 11;                      // M = 2048
  int q = qid & 2047;

  float qx = qc[(b * 3 + 0) * M + q];
  float qy = qc[(b * 3 + 1) * M + q];
  float qz = qc[(b * 3 + 2) * M + q];
  float qn = __fadd_rn(__fadd_rn(__fmul_rn(qx, qx), __fmul_rn(qy, qy)),
                       __fmul_rn(qz, qz));
  f2 qx2 = {qx, qx}, qy2 = {qy, qy}, qz2 = {qz, qz}, qn2 = {qn, qn};

  // distributed top-16: lane (l&15) holds entry (l&15), ascending; all four
  // 16-lane rows mirror the same list (updates are wave-uniform).
  float val = INF;
  int idx = 0;
  float thresh = INF;

  const float* __restrict__ pcb = pc + (size_t)b * 3 * N;

  // dual-candidate sorted-merge round: pops TWO candidates per iteration.
  // merge identity (verified): out_i = min3(val_i, max(val_{i-1}, cl),
  //                                         max(val_{i-2}, ch)),  cl <= ch.
  // candidate extraction/ordering is SALU/SGPR-side (off the VALU chain).
  auto ins2 = [&](u64 m, float dv, int g) {
    do {
      int s1b = __ffsll((long long)m) - 1;  // ascending idx = top_k tie-break
      m &= m - 1;
      int s2b = __ffsll((long long)m) - 1;  // -1 if only one candidate
      m &= m - 1;                           // 0-safe
      float c1 = rdlane_f(dv, s1b);
      float c2 = rdlane_f(dv, s2b < 0 ? 0 : s2b);
      if (s2b < 0) c2 = INF;                // scalar patch
      int ci1 = g + s1b, ci2 = g + s2b;
      bool sw = c2 < c1;                    // strict: tie keeps (c1,c2) order
      float cl = sw ? c2 : c1, ch = sw ? c1 : c2;
      int cil = sw ? ci2 : ci1, cih = sw ? ci1 : ci2;
      // value lane: 2 dpp + 2 max + min3
      float s1v = dpp_shr1_f(val, NINF_BITS);
      float s2v = dpp_shr2_f(val, NINF_BITS);
      float x2 = fmaxf(s1v, cl);
      float x3 = fmaxf(s2v, ch);
      float nv = __builtin_amdgcn_fmed3f(x2, x3, val) ==
                 0.f ? 0.f : fminf(fminf(val, x2), x3);  // (see below)
      // NOTE: use explicit min3 form; the line above is replaced just after
      nv = fminf(fminf(val, x2), x3);
      // index lane
      int s1i = dpp_shr1_i(idx);
      int s2i = dpp_shr2_i(idx);
      bool k1 = x2 < val;
      bool k2 = x3 < val;
      bool use2 = x2 <= x3;                 // tie -> earlier content (branch 2)
      bool insl = cl > s1v;                 // cl inserted here vs shifted-in
      bool insh = ch > s2v;
      int t2 = insl ? cil : s1i;
      int t3 = insh ? cih : s2i;
      int pick = use2 ? t2 : t3;
      idx = (k1 | k2) ? pick : idx;
      val = nv;
    } while (m);
  };

  auto dist = [&](float4 c0, float4 c1) -> f2 {
    // d2 = (qn+pn) + (qx*(-2px)+qy*(-2py)+qz*(-2pz)) == reference bit-exact
    f2 px = {c0.x, c0.y}, py = {c0.z, c0.w};
    f2 pz = {c1.x, c1.y}, pw = {c1.z, c1.w};
    f2 s1 = qx2 * px;
    f2 s2 = qy2 * py;
    f2 s3 = qz2 * pz;
    f2 t = (s1 + s2) + s3;
    return (qn2 + pw) + t;
  };

  if (PACKED) {
    // scalar base + per-lane constant byte offset; double-chunk = 256 pts =
    // 4 dwordx4/lane at imm offsets 0/16/2048/2064, stride 4096 B.
    const char* sbase = (const char*)(pp + (size_t)b * N);
    u32 vo = (u32)(lane << 5);
    auto LD = [&](int dc) {
      const char* p = sbase + ((size_t)dc << 12) + vo;
      Q4 r;
      r.a = *(const float4*)(p);
      r.b = *(const float4*)(p + 16);
      r.c = *(const float4*)(p + 2048);
      r.d = *(const float4*)(p + 2064);
      return r;
    };
    auto half = [&](float dv, int g) {
      u64 m = __ballot(dv < thresh);
      if (m) {
        ins2(m, dv, g);
        thresh = rdlane_f(val, 15);
      }
    };
    auto proc = [&](const Q4& A, int g) {
      f2 dA = dist(A.a, A.b);
      f2 dB = dist(A.c, A.d);   // both up front for ILP
      half(dA.x, g);
      half(dA.y, g + 64);
      half(dB.x, g + 128);
      half(dB.y, g + 192);
    };

    Q4 A = LD(0), Bq = LD(1);
    {
      // ---- warmup on double-chunk 0: bitonic sort first 64 points ----
      f2 dA = dist(A.a, A.b);
      u64 key = ((u64)fkey(__float_as_uint(dA.x)) << 32) | (u32)lane;
#pragma unroll
      for (int k = 2; k <= 64; k <<= 1) {
#pragma unroll
        for (int j = k >> 1; j >= 1; j >>= 1) {
          u32 klo = (u32)key, khi = (u32)(key >> 32);
          u32 plo = (u32)__shfl_xor((int)klo, j);
          u32 phi = (u32)__shfl_xor((int)khi, j);
          u64 pkey = ((u64)phi << 32) | plo;
          bool keepMin = ((lane & j) == 0) == ((lane & k) == 0);
          bool lt = key < pkey;
          key = (lt == keepMin) ? key : pkey;
        }
      }
      {  // distribute sorted entries 0..15 to all four mirror rows
        int src = (lane & 15) << 2;
        u32 lo = (u32)__builtin_amdgcn_ds_bpermute(src, (int)(u32)key);
        u32 hi = (u32)__builtin_amdgcn_ds_bpermute(src, (int)(key >> 32));
        idx = (int)lo;
        val = __uint_as_float(hi ^ (((int)hi >= 0) ? 0xFFFFFFFFu : 0x80000000u));
        thresh = rdlane_f(val, 15);
      }
      half(dA.y, 64);
      f2 dB = dist(A.c, A.d);
      half(dB.x, 128);
      half(dB.y, 192);
    }
    A = LD(2);
    // ---- main loop: ping-pong, reload-in-place, no copies, no wrap ----
#pragma unroll 1
    for (int k = 1; k <= 27; k += 2) {
      proc(Bq, k << 8);
      Bq = LD(k + 2);
      proc(A, (k + 1) << 8);
      A = LD(k + 3);
    }
    proc(Bq, 29 << 8);
    Bq = LD(31);
    proc(A, 30 << 8);
    proc(Bq, 31 << 8);
  } else {
#pragma unroll 1
    for (int g = 0; g < N; g += 64) {
      int n = g + lane;
      float x = pcb[n], y = pcb[N + n], z = pcb[2 * N + n];
      float pn = __fadd_rn(__fadd_rn(__fmul_rn(x, x), __fmul_rn(y, y)),
                           __fmul_rn(z, z));
      float s1 = __fmul_rn(qx, __fmul_rn(x, -2.0f));
      float s2 = __fmul_rn(qy, __fmul_rn(y, -2.0f));
      float s3 = __fmul_rn(qz, __fmul_rn(z, -2.0f));
      float t = __fadd_rn(__fadd_rn(s1, s2), s3);
      float d2 = __fadd_rn(__fadd_rn(qn, pn), t);
      u64 m = __ballot(d2 < thresh);
      if (m) {
        ins2(m, d2, g);
        thresh = rdlane_f(val, 15);
      }
    }
  }

  // ---- finisher (np-faithful): lane (l&15) owns entry (l&15) ----
  float Tv = temp[0];
  float sigma = fmaxf(__fmul_rn(Tv, Tv), 1e-4f);
  float sp = __fadd_rn(sigma, 1e-8f);
  int n = idx;
  float px = pcb[n], py = pcb[N + n], pz = pcb[2 * N + n];
  float dx = __fsub_rn(px, qx), dy = __fsub_rn(py, qy), dz = __fsub_rn(pz, qz);
  float d2w = __fadd_rn(__fadd_rn(__fmul_rn(dx, dx), __fmul_rn(dy, dy)),
                        __fmul_rn(dz, dz));
  float a = -__fdiv_rn(d2w, sp);   // -dist; softmax shift-invariant
  float m = rdlane_f(a, 0);        // entry 0 = nearest (sorted ascending)
  float e = expf(__fsub_rn(a, m));
  float Z = e;
#pragma unroll
  for (int d = 1; d < 16; d <<= 1) Z += __shfl_xor(Z, d, 16);
  float w = __fdiv_rn(e, Z);       // normalized weight
  float sx = __fmul_rn(px, w), sy = __fmul_rn(py, w), sz = __fmul_rn(pz, w);
#pragma unroll
  for (int d = 1; d < 16; d <<= 1) {
    sx += __shfl_xor(sx, d, 16);
    sy += __shfl_xor(sy, d, 16);
    sz += __shfl_xor(sz, d, 16);
  }
  if (lane < 3) {
    float r = (lane == 0) ? sx : ((lane == 1) ? sy : sz);
    out[(b * 3 + lane) * M + q] = r;
  }
}

extern "C" void kernel_launch(void* const* d_in, const int* in_sizes, int n_in,
                              void* d_out, int out_size, void* d_ws, size_t ws_size,
                              hipStream_t stream) {
  const int B = 8, N = 8192, M = 2048;
  const float* pc = (const float*)d_in[0];
  const float* qc = (const float*)d_in[1];
  const float* temp = (const float*)d_in[2];
  float* out = (float*)d_out;

  size_t packBytes = (size_t)B * N * 16;  // B*N/2 pairs * 32B
  bool packed = (ws_size >= packBytes) && (d_ws != nullptr);

  int nblocks = (B * M) / 4;  // 4 queries / 256-thread block (1 per wave)
  if (packed) {
    int R = B * (N >> 1);
    prep_pack2<<<dim3((R + 255) / 256), dim3(256), 0, stream>>>(
        pc, (float4*)d_ws, B, N);
    knn12<true><<<dim3(nblocks), dim3(256), 0, stream>>>(
        pc, qc, temp, (const float4*)d_ws, out, B, N, M);
  } else {
    knn12<false><<<dim3(nblocks), dim3(256), 0, stream>>>(
        pc, qc, temp, nullptr, out, B, N, M);
  }
}

// Round 13
// 79.829 us; speedup vs baseline: 1.2509x; 1.1970x over previous
//
#include <hip/hip_runtime.h>
#include <stdint.h>

typedef unsigned long long u64;
typedef unsigned int u32;
typedef float f2 __attribute__((ext_vector_type(2)));

// ---- cross-lane helpers ----
__device__ __forceinline__ float dpp_shr1_f(float v, int fill_bits) {
  // within each 16-lane row: lane i <- lane i-1; row-lead takes fill
  return __int_as_float(__builtin_amdgcn_update_dpp(
      fill_bits, __float_as_int(v), 0x111 /*row_shr:1*/, 0xF, 0xF, false));
}
__device__ __forceinline__ int dpp_shr1_i(int v) {
  return __builtin_amdgcn_update_dpp(0, v, 0x111, 0xF, 0xF, false);
}
__device__ __forceinline__ float rdlane_f(float v, int lane) {
  return __int_as_float(__builtin_amdgcn_readlane(__float_as_int(v), lane));
}
// order-preserving float-bits -> u32 (monotone over all floats incl. negatives)
__device__ __forceinline__ u32 fkey(u32 s) {
  return s ^ ((u32)((int)s >> 31) | 0x80000000u);
}

// pair records for 128-pt chunks: pair (n0 = k*128+t, n1 = n0+64), t=0..63
// rec0 = {-2x0,-2x1,-2y0,-2y1}, rec1 = {-2z0,-2z1, pn0, pn1}
// x(-2) is exact so q*(-2p) == -2*inner bit-exactly; pn in numpy order.
__global__ void prep_pack2(const float* __restrict__ pc, float4* __restrict__ pp,
                           int B, int N) {
  int r = blockIdx.x * blockDim.x + threadIdx.x;  // pair id
  int H = N >> 1;
  if (r >= B * H) return;
  int b = r / H;
  int j = r - b * H;
  int k = j >> 6, t = j & 63;
  int n0 = (k << 7) + t, n1 = n0 + 64;
  const float* p = pc + (size_t)b * 3 * N;
  float x0 = p[n0], x1 = p[n1];
  float y0 = p[N + n0], y1 = p[N + n1];
  float z0 = p[2 * N + n0], z1 = p[2 * N + n1];
  float pn0 = __fadd_rn(__fadd_rn(__fmul_rn(x0, x0), __fmul_rn(y0, y0)),
                        __fmul_rn(z0, z0));
  float pn1 = __fadd_rn(__fadd_rn(__fmul_rn(x1, x1), __fmul_rn(y1, y1)),
                        __fmul_rn(z1, z1));
  pp[2 * r] = make_float4(__fmul_rn(x0, -2.0f), __fmul_rn(x1, -2.0f),
                          __fmul_rn(y0, -2.0f), __fmul_rn(y1, -2.0f));
  pp[2 * r + 1] = make_float4(__fmul_rn(z0, -2.0f), __fmul_rn(z1, -2.0f),
                              pn0, pn1);
}

struct Q4 { float4 a, b, c, d; };

template <bool PACKED>
__global__ __launch_bounds__(256, 8) void knn13(
    const float* __restrict__ pc,    // (B,3,N)
    const float* __restrict__ qc,    // (B,3,M)
    const float* __restrict__ temp,  // scalar
    const float4* __restrict__ pp,   // packed pair records
    float* __restrict__ out,         // (B,3,M)
    int B, int N, int M) {
#pragma clang fp contract(off)
  const float INF = __int_as_float(0x7f800000);
  const int NINF_BITS = (int)0xff800000;

  int tid = threadIdx.x;
  int lane = tid & 63;
  // wave-uniform query id -> scalar bases (saddr addressing, no VALU addr math)
  int qid = __builtin_amdgcn_readfirstlane(blockIdx.x * 4 + (tid >> 6));
  int b = qid >> 11;                      // M = 2048
  int q = qid & 2047;

  float qx = qc[(b * 3 + 0) * M + q];
  float qy = qc[(b * 3 + 1) * M + q];
  float qz = qc[(b * 3 + 2) * M + q];
  float qn = __fadd_rn(__fadd_rn(__fmul_rn(qx, qx), __fmul_rn(qy, qy)),
                       __fmul_rn(qz, qz));
  f2 qx2 = {qx, qx}, qy2 = {qy, qy}, qz2 = {qz, qz}, qn2 = {qn, qn};

  // distributed top-16: lane (l&15) holds entry (l&15), ascending; all four
  // 16-lane rows mirror the same list (updates are wave-uniform).
  float val = INF;
  int idx = 0;
  float thresh = INF;

  const float* __restrict__ pcb = pc + (size_t)b * 3 * N;

  // serial sorted-insert of candidates in mask (bit s <-> point g+s, ascending)
  auto ins = [&](u64 m, float dv, int g) {
    do {
      int s = __ffsll((long long)m) - 1;  // ascending idx = top_k tie-break
      m &= m - 1;
      float cv = rdlane_f(dv, s);         // wave-uniform candidate
      int ci = g + s;                     // SALU
      float pvv = dpp_shr1_f(val, NINF_BITS);
      int piv = dpp_shr1_i(idx);
      bool p = cv < val;                  // strict < keeps stability
      bool p2 = cv < pvv;
      float nv = __builtin_amdgcn_fmed3f(val, pvv, cv);  // sorted-insert step
      idx = p ? (p2 ? piv : ci) : idx;
      val = nv;
    } while (m);
  };

  auto dist = [&](float4 c0, float4 c1) -> f2 {
    // d2 = (qn+pn) + (qx*(-2px)+qy*(-2py)+qz*(-2pz)) == reference bit-exact
    f2 px = {c0.x, c0.y}, py = {c0.z, c0.w};
    f2 pz = {c1.x, c1.y}, pw = {c1.z, c1.w};
    f2 s1 = qx2 * px;
    f2 s2 = qy2 * py;
    f2 s3 = qz2 * pz;
    f2 t = (s1 + s2) + s3;
    return (qn2 + pw) + t;
  };

  if (PACKED) {
    // scalar base + per-lane constant byte offset; double-chunk = 256 pts =
    // 4 dwordx4/lane at imm offsets 0/16/2048/2064, stride 4096 B.
    const char* sbase = (const char*)(pp + (size_t)b * N);
    u32 vo = (u32)(lane << 5);
    auto LD = [&](int dc) {
      const char* p = sbase + ((size_t)dc << 12) + vo;
      Q4 r;
      r.a = *(const float4*)(p);
      r.b = *(const float4*)(p + 16);
      r.c = *(const float4*)(p + 2048);
      r.d = *(const float4*)(p + 2064);
      return r;
    };
    auto half = [&](float dv, int g) {
      u64 m = __ballot(dv < thresh);
      if (m) {
        ins(m, dv, g);
        thresh = rdlane_f(val, 15);
      }
    };
    auto proc = [&](const Q4& X, int g) {
      f2 dA = dist(X.a, X.b);
      f2 dB = dist(X.c, X.d);   // both up front for ILP
      half(dA.x, g);
      half(dA.y, g + 64);
      half(dB.x, g + 128);
      half(dB.y, g + 192);
    };

    // 3-deep prefetch rotation: ~2 procs (~160-320 cyc) between load and use
    Q4 A = LD(0), Bq = LD(1), Cq = LD(2);
    {
      // ---- warmup on double-chunk 0: bitonic sort first 64 points ----
      f2 dA = dist(A.a, A.b);
      u64 key = ((u64)fkey(__float_as_uint(dA.x)) << 32) | (u32)lane;
#pragma unroll
      for (int k = 2; k <= 64; k <<= 1) {
#pragma unroll
        for (int j = k >> 1; j >= 1; j >>= 1) {
          u32 klo = (u32)key, khi = (u32)(key >> 32);
          u32 plo = (u32)__shfl_xor((int)klo, j);
          u32 phi = (u32)__shfl_xor((int)khi, j);
          u64 pkey = ((u64)phi << 32) | plo;
          bool keepMin = ((lane & j) == 0) == ((lane & k) == 0);
          bool lt = key < pkey;
          key = (lt == keepMin) ? key : pkey;
        }
      }
      {  // distribute sorted entries 0..15 to all four mirror rows
        int src = (lane & 15) << 2;
        u32 lo = (u32)__builtin_amdgcn_ds_bpermute(src, (int)(u32)key);
        u32 hi = (u32)__builtin_amdgcn_ds_bpermute(src, (int)(key >> 32));
        idx = (int)lo;
        val = __uint_as_float(hi ^ (((int)hi >= 0) ? 0xFFFFFFFFu : 0x80000000u));
        thresh = rdlane_f(val, 15);
      }
      half(dA.y, 64);
      f2 dB = dist(A.c, A.d);
      half(dB.x, 128);
      half(dB.y, 192);
    }
    A = LD(3);
    // ---- main loop: rotate A/B/C, reload-in-place, no copies, no wrap ----
    // invariant at loop head: Bq=dc k, Cq=dc k+1, A=dc k+2 (all in flight/ready)
#pragma unroll 1
    for (int k = 1; k <= 25; k += 3) {
      proc(Bq, k << 8);
      Bq = LD(k + 3);
      proc(Cq, (k + 1) << 8);
      Cq = LD(k + 4);
      proc(A, (k + 2) << 8);
      A = LD(k + 5);
    }
    // after loop: Bq=dc28, Cq=dc29, A=dc30 (loaded); dc31 still unissued
    proc(Bq, 28 << 8);
    Bq = LD(31);
    proc(Cq, 29 << 8);
    proc(A, 30 << 8);
    proc(Bq, 31 << 8);
  } else {
#pragma unroll 1
    for (int g = 0; g < N; g += 64) {
      int n = g + lane;
      float x = pcb[n], y = pcb[N + n], z = pcb[2 * N + n];
      float pn = __fadd_rn(__fadd_rn(__fmul_rn(x, x), __fmul_rn(y, y)),
                           __fmul_rn(z, z));
      float s1 = __fmul_rn(qx, __fmul_rn(x, -2.0f));
      float s2 = __fmul_rn(qy, __fmul_rn(y, -2.0f));
      float s3 = __fmul_rn(qz, __fmul_rn(z, -2.0f));
      float t = __fadd_rn(__fadd_rn(s1, s2), s3);
      float d2 = __fadd_rn(__fadd_rn(qn, pn), t);
      u64 m = __ballot(d2 < thresh);
      if (m) {
        ins(m, d2, g);
        thresh = rdlane_f(val, 15);
      }
    }
  }

  // ---- finisher (np-faithful): lane (l&15) owns entry (l&15) ----
  float Tv = temp[0];
  float sigma = fmaxf(__fmul_rn(Tv, Tv), 1e-4f);
  float sp = __fadd_rn(sigma, 1e-8f);
  int n = idx;
  float px = pcb[n], py = pcb[N + n], pz = pcb[2 * N + n];
  float dx = __fsub_rn(px, qx), dy = __fsub_rn(py, qy), dz = __fsub_rn(pz, qz);
  float d2w = __fadd_rn(__fadd_rn(__fmul_rn(dx, dx), __fmul_rn(dy, dy)),
                        __fmul_rn(dz, dz));
  float a = -__fdiv_rn(d2w, sp);   // -dist; softmax shift-invariant
  float m = rdlane_f(a, 0);        // entry 0 = nearest (sorted ascending)
  float e = expf(__fsub_rn(a, m));
  float Z = e;
#pragma unroll
  for (int d = 1; d < 16; d <<= 1) Z += __shfl_xor(Z, d, 16);
  float w = __fdiv_rn(e, Z);       // normalized weight
  float sx = __fmul_rn(px, w), sy = __fmul_rn(py, w), sz = __fmul_rn(pz, w);
#pragma unroll
  for (int d = 1; d < 16; d <<= 1) {
    sx += __shfl_xor(sx, d, 16);
    sy += __shfl_xor(sy, d, 16);
    sz += __shfl_xor(sz, d, 16);
  }
  if (lane < 3) {
    float r = (lane == 0) ? sx : ((lane == 1) ? sy : sz);
    out[(b * 3 + lane) * M + q] = r;
  }
}

extern "C" void kernel_launch(void* const* d_in, const int* in_sizes, int n_in,
                              void* d_out, int out_size, void* d_ws, size_t ws_size,
                              hipStream_t stream) {
  const int B = 8, N = 8192, M = 2048;
  const float* pc = (const float*)d_in[0];
  const float* qc = (const float*)d_in[1];
  const float* temp = (const float*)d_in[2];
  float* out = (float*)d_out;

  size_t packBytes = (size_t)B * N * 16;  // B*N/2 pairs * 32B
  bool packed = (ws_size >= packBytes) && (d_ws != nullptr);

  int nblocks = (B * M) / 4;  // 4 queries / 256-thread block (1 per wave)
  if (packed) {
    int R = B * (N >> 1);
    prep_pack2<<<dim3((R + 255) / 256), dim3(256), 0, stream>>>(
        pc, (float4*)d_ws, B, N);
    knn13<true><<<dim3(nblocks), dim3(256), 0, stream>>>(
        pc, qc, temp, (const float4*)d_ws, out, B, N, M);
  } else {
    knn13<false><<<dim3(nblocks), dim3(256), 0, stream>>>(
        pc, qc, temp, nullptr, out, B, N, M);
  }
}

// Round 14
// 78.161 us; speedup vs baseline: 1.2776x; 1.0213x over previous
//
#include <hip/hip_runtime.h>
#include <stdint.h>

typedef unsigned long long u64;
typedef unsigned int u32;
typedef float f2 __attribute__((ext_vector_type(2)));
typedef float f4 __attribute__((ext_vector_type(4)));

// ---- cross-lane helpers ----
__device__ __forceinline__ float dpp_shr1_f(float v, int fill_bits) {
  // within each 16-lane row: lane i <- lane i-1; row-lead takes fill
  return __int_as_float(__builtin_amdgcn_update_dpp(
      fill_bits, __float_as_int(v), 0x111 /*row_shr:1*/, 0xF, 0xF, false));
}
__device__ __forceinline__ int dpp_shr1_i(int v) {
  return __builtin_amdgcn_update_dpp(0, v, 0x111, 0xF, 0xF, false);
}
__device__ __forceinline__ float rdlane_f(float v, int lane) {
  return __int_as_float(__builtin_amdgcn_readlane(__float_as_int(v), lane));
}
// order-preserving float-bits -> u32 (monotone over all floats incl. negatives)
__device__ __forceinline__ u32 fkey(u32 s) {
  return s ^ ((u32)((int)s >> 31) | 0x80000000u);
}

// pair records for 128-pt chunks: pair (n0 = k*128+t, n1 = n0+64), t=0..63
// rec0 = {-2x0,-2x1,-2y0,-2y1}, rec1 = {-2z0,-2z1, pn0, pn1}
// x(-2) is exact so q*(-2p) == -2*inner bit-exactly; pn in numpy order.
__global__ void prep_pack2(const float* __restrict__ pc, float4* __restrict__ pp,
                           int B, int N) {
  int r = blockIdx.x * blockDim.x + threadIdx.x;  // pair id
  int H = N >> 1;
  if (r >= B * H) return;
  int b = r / H;
  int j = r - b * H;
  int k = j >> 6, t = j & 63;
  int n0 = (k << 7) + t, n1 = n0 + 64;
  const float* p = pc + (size_t)b * 3 * N;
  float x0 = p[n0], x1 = p[n1];
  float y0 = p[N + n0], y1 = p[N + n1];
  float z0 = p[2 * N + n0], z1 = p[2 * N + n1];
  float pn0 = __fadd_rn(__fadd_rn(__fmul_rn(x0, x0), __fmul_rn(y0, y0)),
                        __fmul_rn(z0, z0));
  float pn1 = __fadd_rn(__fadd_rn(__fmul_rn(x1, x1), __fmul_rn(y1, y1)),
                        __fmul_rn(z1, z1));
  pp[2 * r] = make_float4(__fmul_rn(x0, -2.0f), __fmul_rn(x1, -2.0f),
                          __fmul_rn(y0, -2.0f), __fmul_rn(y1, -2.0f));
  pp[2 * r + 1] = make_float4(__fmul_rn(z0, -2.0f), __fmul_rn(z1, -2.0f),
                              pn0, pn1);
}

struct Q2 { f4 a, b; };

template <bool PACKED>
__global__ __launch_bounds__(256, 8) void knn14(
    const float* __restrict__ pc,    // (B,3,N)
    const float* __restrict__ qc,    // (B,3,M)
    const float* __restrict__ temp,  // scalar
    const float4* __restrict__ pp,   // packed pair records
    float* __restrict__ out,         // (B,3,M)
    int B, int N, int M) {
#pragma clang fp contract(off)
  const float INF = __int_as_float(0x7f800000);
  const int NINF_BITS = (int)0xff800000;

  int tid = threadIdx.x;
  int lane = tid & 63;
  // wave-uniform query id -> scalar bases (saddr addressing, no VALU addr math)
  int qid = __builtin_amdgcn_readfirstlane(blockIdx.x * 4 + (tid >> 6));
  int b = qid >> 11;                      // M = 2048
  int q = qid & 2047;

  float qx = qc[(b * 3 + 0) * M + q];
  float qy = qc[(b * 3 + 1) * M + q];
  float qz = qc[(b * 3 + 2) * M + q];
  float qn = __fadd_rn(__fadd_rn(__fmul_rn(qx, qx), __fmul_rn(qy, qy)),
                       __fmul_rn(qz, qz));
  f2 qx2 = {qx, qx}, qy2 = {qy, qy}, qz2 = {qz, qz}, qn2 = {qn, qn};

  // distributed top-16: lane (l&15) holds entry (l&15), ascending; all four
  // 16-lane rows mirror the same list (updates are wave-uniform).
  float val = INF;
  int idx = 0;
  float thresh = INF;

  const float* __restrict__ pcb = pc + (size_t)b * 3 * N;

  // serial sorted-insert of candidates in mask (bit s <-> point g+s, ascending)
  auto ins = [&](u64 m, float dv, int g) {
    do {
      int s = __ffsll((long long)m) - 1;  // ascending idx = top_k tie-break
      m &= m - 1;
      float cv = rdlane_f(dv, s);         // wave-uniform candidate
      int ci = g + s;                     // SALU
      float pvv = dpp_shr1_f(val, NINF_BITS);
      int piv = dpp_shr1_i(idx);
      bool p = cv < val;                  // strict < keeps stability
      bool p2 = cv < pvv;
      float nv = __builtin_amdgcn_fmed3f(val, pvv, cv);  // sorted-insert step
      idx = p ? (p2 ? piv : ci) : idx;
      val = nv;
    } while (m);
  };

  auto dist = [&](f4 c0, f4 c1) -> f2 {
    // d2 = (qn+pn) + (qx*(-2px)+qy*(-2py)+qz*(-2pz)) == reference bit-exact
    f2 px = {c0[0], c0[1]}, py = {c0[2], c0[3]};
    f2 pz = {c1[0], c1[1]}, pw = {c1[2], c1[3]};
    f2 s1 = qx2 * px;
    f2 s2 = qy2 * py;
    f2 s3 = qz2 * pz;
    f2 t = (s1 + s2) + s3;
    return (qn2 + pw) + t;
  };

  if (PACKED) {
    // scalar base; per-lane constant byte offset lane*32; chunk stride 2048 B.
    // Loads are inline-asm so the compiler can neither sink nor retime them;
    // counted vmcnt(N) keeps 3 chunk-loads in flight across procs (T3/T4).
    const char* sbase = (const char*)(pp + (size_t)b * N);
    u32 vo = (u32)(lane << 5);
    auto LD = [&](int dc) -> Q2 {
      Q2 r;
      const char* p = sbase + ((size_t)dc << 11);  // uniform -> SGPR pair
      asm volatile(
          "global_load_dwordx4 %0, %2, %3 offset:0\n\t"
          "global_load_dwordx4 %1, %2, %3 offset:16"
          : "=&v"(r.a), "=&v"(r.b)
          : "v"(vo), "s"(p));
      return r;
    };
    auto half = [&](float dv, int g) {
      u64 m = __ballot(dv < thresh);
      if (m) {
        ins(m, dv, g);
        thresh = rdlane_f(val, 15);
      }
    };
    auto proc = [&](const Q2& X, int c) {
      f2 d = dist(X.a, X.b);
      int g = c << 7;
      half(d.x, g);
      half(d.y, g + 64);
    };

    Q2 A = LD(0), Bq = LD(1), Cq = LD(2), Dq = LD(3);
    asm volatile("s_waitcnt vmcnt(6)");
    __builtin_amdgcn_sched_barrier(0);
    {
      // ---- warmup on chunk 0: bitonic sort first 64 points ----
      f2 dA = dist(A.a, A.b);
      u64 key = ((u64)fkey(__float_as_uint(dA.x)) << 32) | (u32)lane;
#pragma unroll
      for (int k = 2; k <= 64; k <<= 1) {
#pragma unroll
        for (int j = k >> 1; j >= 1; j >>= 1) {
          u32 klo = (u32)key, khi = (u32)(key >> 32);
          u32 plo = (u32)__shfl_xor((int)klo, j);
          u32 phi = (u32)__shfl_xor((int)khi, j);
          u64 pkey = ((u64)phi << 32) | plo;
          bool keepMin = ((lane & j) == 0) == ((lane & k) == 0);
          bool lt = key < pkey;
          key = (lt == keepMin) ? key : pkey;
        }
      }
      {  // distribute sorted entries 0..15 to all four mirror rows
        int src = (lane & 15) << 2;
        u32 lo = (u32)__builtin_amdgcn_ds_bpermute(src, (int)(u32)key);
        u32 hi = (u32)__builtin_amdgcn_ds_bpermute(src, (int)(key >> 32));
        idx = (int)lo;
        val = __uint_as_float(hi ^ (((int)hi >= 0) ? 0xFFFFFFFFu : 0x80000000u));
        thresh = rdlane_f(val, 15);
      }
      half(dA.y, 64);
    }
    A = LD(4);
    asm volatile("s_waitcnt vmcnt(6)");
    __builtin_amdgcn_sched_barrier(0);
    proc(Bq, 1);
    Bq = LD(5);
    asm volatile("s_waitcnt vmcnt(6)");
    __builtin_amdgcn_sched_barrier(0);
    proc(Cq, 2);
    Cq = LD(6);
    asm volatile("s_waitcnt vmcnt(6)");
    __builtin_amdgcn_sched_barrier(0);
    proc(Dq, 3);
    Dq = LD(7);
    // ---- main loop: 4-buffer rotation, counted vmcnt keeps 3 LDs in flight
#pragma unroll 1
    for (int k = 4; k <= 56; k += 4) {
      asm volatile("s_waitcnt vmcnt(6)");
      __builtin_amdgcn_sched_barrier(0);
      proc(A, k);
      A = LD(k + 4);
      asm volatile("s_waitcnt vmcnt(6)");
      __builtin_amdgcn_sched_barrier(0);
      proc(Bq, k + 1);
      Bq = LD(k + 5);
      asm volatile("s_waitcnt vmcnt(6)");
      __builtin_amdgcn_sched_barrier(0);
      proc(Cq, k + 2);
      Cq = LD(k + 6);
      asm volatile("s_waitcnt vmcnt(6)");
      __builtin_amdgcn_sched_barrier(0);
      proc(Dq, k + 3);
      Dq = LD(k + 7);
    }
    // after loop: A=60, Bq=61, Cq=62, Dq=63 in flight; drain 6->4->2->0
    asm volatile("s_waitcnt vmcnt(6)");
    __builtin_amdgcn_sched_barrier(0);
    proc(A, 60);
    asm volatile("s_waitcnt vmcnt(4)");
    __builtin_amdgcn_sched_barrier(0);
    proc(Bq, 61);
    asm volatile("s_waitcnt vmcnt(2)");
    __builtin_amdgcn_sched_barrier(0);
    proc(Cq, 62);
    asm volatile("s_waitcnt vmcnt(0)");
    __builtin_amdgcn_sched_barrier(0);
    proc(Dq, 63);
  } else {
#pragma unroll 1
    for (int g = 0; g < N; g += 64) {
      int n = g + lane;
      float x = pcb[n], y = pcb[N + n], z = pcb[2 * N + n];
      float pn = __fadd_rn(__fadd_rn(__fmul_rn(x, x), __fmul_rn(y, y)),
                           __fmul_rn(z, z));
      float s1 = __fmul_rn(qx, __fmul_rn(x, -2.0f));
      float s2 = __fmul_rn(qy, __fmul_rn(y, -2.0f));
      float s3 = __fmul_rn(qz, __fmul_rn(z, -2.0f));
      float t = __fadd_rn(__fadd_rn(s1, s2), s3);
      float d2 = __fadd_rn(__fadd_rn(qn, pn), t);
      u64 m = __ballot(d2 < thresh);
      if (m) {
        ins(m, d2, g);
        thresh = rdlane_f(val, 15);
      }
    }
  }

  // ---- finisher (np-faithful): lane (l&15) owns entry (l&15) ----
  float Tv = temp[0];
  float sigma = fmaxf(__fmul_rn(Tv, Tv), 1e-4f);
  float sp = __fadd_rn(sigma, 1e-8f);
  int n = idx;
  float px = pcb[n], py = pcb[N + n], pz = pcb[2 * N + n];
  float dx = __fsub_rn(px, qx), dy = __fsub_rn(py, qy), dz = __fsub_rn(pz, qz);
  float d2w = __fadd_rn(__fadd_rn(__fmul_rn(dx, dx), __fmul_rn(dy, dy)),
                        __fmul_rn(dz, dz));
  float a = -__fdiv_rn(d2w, sp);   // -dist; softmax shift-invariant
  float m = rdlane_f(a, 0);        // entry 0 = nearest (sorted ascending)
  float e = expf(__fsub_rn(a, m));
  float Z = e;
#pragma unroll
  for (int d = 1; d < 16; d <<= 1) Z += __shfl_xor(Z, d, 16);
  float w = __fdiv_rn(e, Z);       // normalized weight
  float sx = __fmul_rn(px, w), sy = __fmul_rn(py, w), sz = __fmul_rn(pz, w);
#pragma unroll
  for (int d = 1; d < 16; d <<= 1) {
    sx += __shfl_xor(sx, d, 16);
    sy += __shfl_xor(sy, d, 16);
    sz += __shfl_xor(sz, d, 16);
  }
  if (lane < 3) {
    float r = (lane == 0) ? sx : ((lane == 1) ? sy : sz);
    out[(b * 3 + lane) * M + q] = r;
  }
}

extern "C" void kernel_launch(void* const* d_in, const int* in_sizes, int n_in,
                              void* d_out, int out_size, void* d_ws, size_t ws_size,
                              hipStream_t stream) {
  const int B = 8, N = 8192, M = 2048;
  const float* pc = (const float*)d_in[0];
  const float* qc = (const float*)d_in[1];
  const float* temp = (const float*)d_in[2];
  float* out = (float*)d_out;

  size_t packBytes = (size_t)B * N * 16;  // B*N/2 pairs * 32B
  bool packed = (ws_size >= packBytes) && (d_ws != nullptr);

  int nblocks = (B * M) / 4;  // 4 queries / 256-thread block (1 per wave)
  if (packed) {
    int R = B * (N >> 1);
    prep_pack2<<<dim3((R + 255) / 256), dim3(256), 0, stream>>>(
        pc, (float4*)d_ws, B, N);
    knn14<true><<<dim3(nblocks), dim3(256), 0, stream>>>(
        pc, qc, temp, (const float4*)d_ws, out, B, N, M);
  } else {
    knn14<false><<<dim3(nblocks), dim3(256), 0, stream>>>(
        pc, qc, temp, nullptr, out, B, N, M);
  }
}

// Round 15
// 70.361 us; speedup vs baseline: 1.4192x; 1.1109x over previous
//
#include <hip/hip_runtime.h>
#include <stdint.h>

typedef unsigned long long u64;
typedef unsigned int u32;
typedef float f2 __attribute__((ext_vector_type(2)));
typedef float f4 __attribute__((ext_vector_type(4)));

// ---- cross-lane helpers ----
__device__ __forceinline__ float dpp_shr1_f(float v, int fill_bits) {
  // within each 16-lane row: lane i <- lane i-1; row-lead takes fill
  return __int_as_float(__builtin_amdgcn_update_dpp(
      fill_bits, __float_as_int(v), 0x111 /*row_shr:1*/, 0xF, 0xF, false));
}
__device__ __forceinline__ int dpp_shr1_i(int v) {
  return __builtin_amdgcn_update_dpp(0, v, 0x111, 0xF, 0xF, false);
}
__device__ __forceinline__ float rdlane_f(float v, int lane) {
  return __int_as_float(__builtin_amdgcn_readlane(__float_as_int(v), lane));
}
// order-preserving float-bits -> u32 (monotone over all floats incl. negatives)
__device__ __forceinline__ u32 fkey(u32 s) {
  return s ^ ((u32)((int)s >> 31) | 0x80000000u);
}

// pair records for 128-pt chunks: pair (n0 = k*128+t, n1 = n0+64), t=0..63
// rec0 = {-2x0,-2x1,-2y0,-2y1}, rec1 = {-2z0,-2z1, pn0, pn1}
// x(-2) is exact so q*(-2p) == -2*inner bit-exactly; pn in numpy order.
__global__ void prep_pack2(const float* __restrict__ pc, float4* __restrict__ pp,
                           int B, int N) {
  int r = blockIdx.x * blockDim.x + threadIdx.x;  // pair id
  int H = N >> 1;
  if (r >= B * H) return;
  int b = r / H;
  int j = r - b * H;
  int k = j >> 6, t = j & 63;
  int n0 = (k << 7) + t, n1 = n0 + 64;
  const float* p = pc + (size_t)b * 3 * N;
  float x0 = p[n0], x1 = p[n1];
  float y0 = p[N + n0], y1 = p[N + n1];
  float z0 = p[2 * N + n0], z1 = p[2 * N + n1];
  float pn0 = __fadd_rn(__fadd_rn(__fmul_rn(x0, x0), __fmul_rn(y0, y0)),
                        __fmul_rn(z0, z0));
  float pn1 = __fadd_rn(__fadd_rn(__fmul_rn(x1, x1), __fmul_rn(y1, y1)),
                        __fmul_rn(z1, z1));
  pp[2 * r] = make_float4(__fmul_rn(x0, -2.0f), __fmul_rn(x1, -2.0f),
                          __fmul_rn(y0, -2.0f), __fmul_rn(y1, -2.0f));
  pp[2 * r + 1] = make_float4(__fmul_rn(z0, -2.0f), __fmul_rn(z1, -2.0f),
                              pn0, pn1);
}

template <bool PACKED>
__global__ __launch_bounds__(256, 8) void knn15(
    const float* __restrict__ pc,    // (B,3,N)
    const float* __restrict__ qc,    // (B,3,M)
    const float* __restrict__ temp,  // scalar
    const float4* __restrict__ pp,   // packed pair records
    float* __restrict__ out,         // (B,3,M)
    int B, int N, int M) {
#pragma clang fp contract(off)
  const float INF = __int_as_float(0x7f800000);
  const int NINF_BITS = (int)0xff800000;

  // double-buffered super-chunks: 2 x 512 pts x 16 B = 16 KiB
  __shared__ __attribute__((aligned(16))) char smem[16384];

  int tid = threadIdx.x;
  int lane = tid & 63;
  int widx = tid >> 6;  // wave 0..3; also this wave's staging chunk
  // wave-uniform query id -> scalar bases; 4 waves of a block share batch b
  int qid = __builtin_amdgcn_readfirstlane(blockIdx.x * 4 + widx);
  int b = qid >> 11;                      // M = 2048; 512 blocks per batch
  int q = qid & 2047;

  float qx = qc[(b * 3 + 0) * M + q];
  float qy = qc[(b * 3 + 1) * M + q];
  float qz = qc[(b * 3 + 2) * M + q];
  float qn = __fadd_rn(__fadd_rn(__fmul_rn(qx, qx), __fmul_rn(qy, qy)),
                       __fmul_rn(qz, qz));
  f2 qx2 = {qx, qx}, qy2 = {qy, qy}, qz2 = {qz, qz}, qn2 = {qn, qn};

  // distributed top-16: lane (l&15) holds entry (l&15), ascending; all four
  // 16-lane rows mirror the same list (updates are wave-uniform).
  float val = INF;
  int idx = 0;
  float thresh = INF;

  const float* __restrict__ pcb = pc + (size_t)b * 3 * N;

  // serial sorted-insert of candidates in mask (bit s <-> point g+s, ascending)
  auto ins = [&](u64 m, float dv, int g) {
    do {
      int s = __ffsll((long long)m) - 1;  // ascending idx = top_k tie-break
      m &= m - 1;
      float cv = rdlane_f(dv, s);         // wave-uniform candidate
      int ci = g + s;                     // SALU
      float pvv = dpp_shr1_f(val, NINF_BITS);
      int piv = dpp_shr1_i(idx);
      bool p = cv < val;                  // strict < keeps stability
      bool p2 = cv < pvv;
      float nv = __builtin_amdgcn_fmed3f(val, pvv, cv);  // sorted-insert step
      idx = p ? (p2 ? piv : ci) : idx;
      val = nv;
    } while (m);
  };

  auto dist = [&](f4 c0, f4 c1) -> f2 {
    // d2 = (qn+pn) + (qx*(-2px)+qy*(-2py)+qz*(-2pz)) == reference bit-exact
    f2 px = {c0[0], c0[1]}, py = {c0[2], c0[3]};
    f2 pz = {c1[0], c1[1]}, pw = {c1[2], c1[3]};
    f2 s1 = qx2 * px;
    f2 s2 = qy2 * py;
    f2 s3 = qz2 * pz;
    f2 t = (s1 + s2) + s3;
    return (qn2 + pw) + t;
  };

  if (PACKED) {
    const char* sbase = (const char*)(pp + (size_t)b * N);  // block-uniform
    u32 go = (u32)((widx << 11) + (lane << 5));  // this wave's global stage off
    u32 lo16 = (u32)(lane << 4);

    f4 s0, s1;  // reg staging (T14: load early, write late)
    auto stageLoad = [&](int t) {
      const char* p = sbase + ((size_t)t << 13) + go;
      s0 = *(const f4*)p;
      s1 = *(const f4*)(p + 16);
    };
    auto stageWrite = [&](int buf) {
      // chunk widx of super: plane0 at +0, plane1 at +1024 (stride-16 lanes,
      // conflict-free: 8 consecutive lanes cover all 32 banks)
      char* d = &smem[(buf << 13) + (widx << 11)];
      *(f4*)(d + lo16) = s0;
      *(f4*)(d + 1024 + lo16) = s1;
    };
    auto half = [&](float dv, int g) {
      u64 m = __ballot(dv < thresh);
      if (m) {
        ins(m, dv, g);
        thresh = rdlane_f(val, 15);
      }
    };
    auto procChunk = [&](int buf, int c, int gbase) {
      const char* s = &smem[(buf << 13) + (c << 11)];
      f4 c0 = *(const f4*)(s + lo16);
      f4 c1 = *(const f4*)(s + 1024 + lo16);
      f2 d = dist(c0, c1);
      half(d.x, gbase);
      half(d.y, gbase + 64);
    };

    stageLoad(0);
    stageWrite(0);
    __syncthreads();
    stageLoad(1);
    {
      // ---- warmup: super 0 chunk 0, bitonic sort first 64 points ----
      const char* s = &smem[0];
      f4 c0 = *(const f4*)(s + lo16);
      f4 c1 = *(const f4*)(s + 1024 + lo16);
      f2 dA = dist(c0, c1);
      u64 key = ((u64)fkey(__float_as_uint(dA.x)) << 32) | (u32)lane;
#pragma unroll
      for (int k = 2; k <= 64; k <<= 1) {
#pragma unroll
        for (int j = k >> 1; j >= 1; j >>= 1) {
          u32 klo = (u32)key, khi = (u32)(key >> 32);
          u32 plo = (u32)__shfl_xor((int)klo, j);
          u32 phi = (u32)__shfl_xor((int)khi, j);
          u64 pkey = ((u64)phi << 32) | plo;
          bool keepMin = ((lane & j) == 0) == ((lane & k) == 0);
          bool lt = key < pkey;
          key = (lt == keepMin) ? key : pkey;
        }
      }
      {  // distribute sorted entries 0..15 to all four mirror rows
        int src = (lane & 15) << 2;
        u32 lo = (u32)__builtin_amdgcn_ds_bpermute(src, (int)(u32)key);
        u32 hi = (u32)__builtin_amdgcn_ds_bpermute(src, (int)(key >> 32));
        idx = (int)lo;
        val = __uint_as_float(hi ^ (((int)hi >= 0) ? 0xFFFFFFFFu : 0x80000000u));
        thresh = rdlane_f(val, 15);
      }
      half(dA.y, 64);
      procChunk(0, 1, 128);
      procChunk(0, 2, 256);
      procChunk(0, 3, 384);
    }
    stageWrite(1);
    __syncthreads();
    // ---- main loop over supers 1..14: stage t+1 while processing t ----
#pragma unroll 1
    for (int t = 1; t < 15; ++t) {
      stageLoad(t + 1);            // issue early; lands during processing
      int buf = t & 1;
      int gb = t << 9;
      procChunk(buf, 0, gb);
      procChunk(buf, 1, gb + 128);
      procChunk(buf, 2, gb + 256);
      procChunk(buf, 3, gb + 384);
      stageWrite((t + 1) & 1);     // vmcnt wait here is ~free (loads landed)
      __syncthreads();
    }
    {  // last super (15), no staging
      int gb = 15 << 9;
      procChunk(1, 0, gb);
      procChunk(1, 1, gb + 128);
      procChunk(1, 2, gb + 256);
      procChunk(1, 3, gb + 384);
    }
  } else {
#pragma unroll 1
    for (int g = 0; g < N; g += 64) {
      int n = g + lane;
      float x = pcb[n], y = pcb[N + n], z = pcb[2 * N + n];
      float pn = __fadd_rn(__fadd_rn(__fmul_rn(x, x), __fmul_rn(y, y)),
                           __fmul_rn(z, z));
      float s1 = __fmul_rn(qx, __fmul_rn(x, -2.0f));
      float s2 = __fmul_rn(qy, __fmul_rn(y, -2.0f));
      float s3 = __fmul_rn(qz, __fmul_rn(z, -2.0f));
      float t = __fadd_rn(__fadd_rn(s1, s2), s3);
      float d2 = __fadd_rn(__fadd_rn(qn, pn), t);
      u64 m = __ballot(d2 < thresh);
      if (m) {
        ins(m, d2, g);
        thresh = rdlane_f(val, 15);
      }
    }
  }

  // ---- finisher (np-faithful): lane (l&15) owns entry (l&15) ----
  float Tv = temp[0];
  float sigma = fmaxf(__fmul_rn(Tv, Tv), 1e-4f);
  float sp = __fadd_rn(sigma, 1e-8f);
  int n = idx;
  float px = pcb[n], py = pcb[N + n], pz = pcb[2 * N + n];
  float dx = __fsub_rn(px, qx), dy = __fsub_rn(py, qy), dz = __fsub_rn(pz, qz);
  float d2w = __fadd_rn(__fadd_rn(__fmul_rn(dx, dx), __fmul_rn(dy, dy)),
                        __fmul_rn(dz, dz));
  float a = -__fdiv_rn(d2w, sp);   // -dist; softmax shift-invariant
  float m = rdlane_f(a, 0);        // entry 0 = nearest (sorted ascending)
  float e = expf(__fsub_rn(a, m));
  float Z = e;
#pragma unroll
  for (int d = 1; d < 16; d <<= 1) Z += __shfl_xor(Z, d, 16);
  float w = __fdiv_rn(e, Z);       // normalized weight
  float sx = __fmul_rn(px, w), sy = __fmul_rn(py, w), sz = __fmul_rn(pz, w);
#pragma unroll
  for (int d = 1; d < 16; d <<= 1) {
    sx += __shfl_xor(sx, d, 16);
    sy += __shfl_xor(sy, d, 16);
    sz += __shfl_xor(sz, d, 16);
  }
  if (lane < 3) {
    float r = (lane == 0) ? sx : ((lane == 1) ? sy : sz);
    out[(b * 3 + lane) * M + q] = r;
  }
}

extern "C" void kernel_launch(void* const* d_in, const int* in_sizes, int n_in,
                              void* d_out, int out_size, void* d_ws, size_t ws_size,
                              hipStream_t stream) {
  const int B = 8, N = 8192, M = 2048;
  const float* pc = (const float*)d_in[0];
  const float* qc = (const float*)d_in[1];
  const float* temp = (const float*)d_in[2];
  float* out = (float*)d_out;

  size_t packBytes = (size_t)B * N * 16;  // B*N/2 pairs * 32B
  bool packed = (ws_size >= packBytes) && (d_ws != nullptr);

  int nblocks = (B * M) / 4;  // 4 queries / 256-thread block (1 per wave)
  if (packed) {
    int R = B * (N >> 1);
    prep_pack2<<<dim3((R + 255) / 256), dim3(256), 0, stream>>>(
        pc, (float4*)d_ws, B, N);
    knn15<true><<<dim3(nblocks), dim3(256), 0, stream>>>(
        pc, qc, temp, (const float4*)d_ws, out, B, N, M);
  } else {
    knn15<false><<<dim3(nblocks), dim3(256), 0, stream>>>(
        pc, qc, temp, nullptr, out, B, N, M);
  }
}